// Round 7
// baseline (4127.309 us; speedup 1.0000x reference)
//
#include <hip/hip_runtime.h>
#include <math.h>

#define BB 16
#define TT 144
#define TP1 145
#define HW4 4096   // f4 groups per image
#define HW8 2048   // f8/u16x8 groups per image
#define LL 6
#define BIGE 1e30
#define EPSQ 7.62951e-6  // 0.5/65535 quantization bound on w in [0,1]

typedef float          f4    __attribute__((ext_vector_type(4)));
typedef float          f8    __attribute__((ext_vector_type(8)));
typedef unsigned short u16x4 __attribute__((ext_vector_type(4)));
typedef unsigned short u16x8 __attribute__((ext_vector_type(8)));
typedef unsigned long long ull;

// ---- workspace layout (bytes) ----
static const size_t OFF_A     = 0;                    // B*HW f32 (1 MB each)
static const size_t OFF_M     = 1u << 20;
static const size_t OFF_U     = 2u << 20;
static const size_t OFF_V     = 3u << 20;
static const size_t OFF_ERR32 = 4u << 20;             // B*145 f64 (build exact scores)
static const size_t OFF_ERR16 = (4u << 20) + 32768;   // B*145 f64 (per-step screen)
static const size_t OFF_ERRX  = (4u << 20) + 65536;   // B*145 f64 (rare exact re-evals)
static const size_t OFF_D     = (4u << 20) + 98304;   // B f64
static const size_t OFF_USED  = (4u << 20) + 102400;  // B*145 i32
static const size_t OFF_PROT  = (4u << 20) + 114688;  // protocol ints/masks (~7 KB)
static const size_t OFF_WQ    = (4u << 20) + 131072;  // B*T*HW u16 = 75,497,472
static const size_t WS_FULL   = OFF_WQ + 75497472ull;

// protocol int layout (per (l,b): idx = l*16+b, 96 slots)
#define P_DONE1 0
#define P_STAT1 96
#define P_SELF  192
#define P_DONE2 288
#define P_SCNT  384
#define P_NINT  512          // masks (ull[96][3]) start at ip + P_NINT

__device__ __forceinline__ float hsum(f4 v) { return ((v.x + v.y) + v.z) + v.w; }
__device__ __forceinline__ float hsum8(f8 v) {
    return (((v.s0 + v.s1) + (v.s2 + v.s3)) + ((v.s4 + v.s5) + (v.s6 + v.s7)));
}

__device__ __forceinline__ double wave_reduce(double s) {
    for (int off = 32; off; off >>= 1) s += __shfl_down(s, off);
    return s;  // valid in lane 0
}

__device__ __forceinline__ double blk_reduce(double s) {
    for (int off = 32; off; off >>= 1) s += __shfl_down(s, off);
    __shared__ double smr[4];
    if ((threadIdx.x & 63) == 0) smr[threadIdx.x >> 6] = s;
    __syncthreads();
    return smr[0] + smr[1] + smr[2] + smr[3];
}

// Build wq = u16(round(65535*w)), w = t*m + bg*(1-m) f32; EXACT step-0 scores;
// zero used[] and the protocol block. temps/masks read-once -> non-temporal.
__global__ void k_build(const f4* __restrict__ temps, const f4* __restrict__ masks,
                        const f4* __restrict__ bg, const f4* __restrict__ x,
                        u16x4* __restrict__ wq, double* __restrict__ err32,
                        int* __restrict__ used, int* __restrict__ prot) {
    const int t = blockIdx.x, b = blockIdx.y, tid = threadIdx.x;
    const f4* xb = x + (size_t)b * HW4;
    double s = 0.0;
    if (t == 0) {
        if (tid < TP1) used[b * TP1 + tid] = 0;
        if (b == 0) for (int i = tid; i < P_NINT + 96 * 6; i += 256) prot[i] = 0;
        for (int j = tid; j < HW4; j += 256)
            s += (double)(100.f - 10.f * hsum(xb[j]));
    } else {
        const size_t row = ((size_t)(b * TT + t - 1)) * HW4;
        for (int j = tid; j < HW4; j += 256) {
            f4 tv = __builtin_nontemporal_load(&temps[row + j]);
            f4 mv = __builtin_nontemporal_load(&masks[row + j]);
            f4 bv = bg[j], xv = xb[j];
            f4 w = tv * mv + bv * (1.f - mv);
            wq[row + j] = __builtin_convertvector(w * 65535.f + 0.5f, u16x4);
            s += (double)hsum(w * (w - 2.f * xv));
        }
    }
    double tot = blk_reduce(s);
    if (tid == 0) err32[b * TP1 + t] = tot;
}

// Fused per-step kernel: screen + resolve + (rare) exact refine + state update.
// One wave per (b,t); ALL 2320 blocks guaranteed co-resident (launch_bounds(64,4)
// => VGPR<=128 => >=16 blocks/CU; need only 10/CU), so intra-batch spin is safe.
template <bool LAST>
__global__ __launch_bounds__(64, 4) void k_fstep(
    const f4* __restrict__ temps, const f4* __restrict__ masks,
    const f4* __restrict__ bg, const f4* __restrict__ x,
    const u16x8* __restrict__ wq, const f4* __restrict__ u4, const f4* __restrict__ v4,
    f4* __restrict__ A, f4* __restrict__ M,
    int* __restrict__ used, double* __restrict__ err16, double* __restrict__ errx,
    double* __restrict__ Dd, int* __restrict__ prot,
    f4* __restrict__ out_obj, f4* __restrict__ out_msk, f4* __restrict__ out_rec,
    float* __restrict__ out_ids, int l) {
    const int wg = blockIdx.x;
    const int b = wg / TP1;
    const int t = wg - b * TP1;
    const int lane = threadIdx.x;
    const int lb = l * 16 + b;
    int* done1 = prot + P_DONE1;
    int* stat1 = prot + P_STAT1;
    int* selfp = prot + P_SELF;
    int* done2 = prot + P_DONE2;
    int* scnt  = prot + P_SCNT;
    ull* maskp = (ull*)(prot + P_NINT) + (size_t)lb * 3;

    const f4* ub = u4 + (size_t)b * HW4;
    const f4* vb = v4 + (size_t)b * HW4;
    double* e16 = err16 + (size_t)b * TP1;

    // ---- Phase A: screen score for (b,t) ----
    if (t != 0 && used[b * TP1 + t]) {
        if (lane == 0) e16[t] = BIGE;
    } else if (t == 0) {
        double s = 0.0, d = 0.0;
        for (int j = lane; j < HW4; j += 64) {
            f4 uu = ub[j], vv = vb[j];
            s += (double)(25.f * hsum(vv) - 10.f * hsum(uu));
            f4 au = {fabsf(uu.x), fabsf(uu.y), fabsf(uu.z), fabsf(uu.w)};
            d += (double)hsum(vv + au);
        }
        for (int off = 32; off; off >>= 1) { s += __shfl_down(s, off); d += __shfl_down(d, off); }
        if (lane == 0) { Dd[b] = d; e16[0] = s; }
    } else {
        const f8* ub8 = (const f8*)ub;
        const f8* vb8 = (const f8*)vb;
        const u16x8* wrow = wq + ((size_t)(b * TT + t - 1)) * HW8;
        double s = 0.0;
        #pragma unroll 4
        for (int j = lane; j < HW8; j += 64) {
            f8 w = __builtin_convertvector(wrow[j], f8) * (1.f / 65535.f);
            f8 uu = ub8[j], vv = vb8[j];
            s += (double)hsum8(w * (vv * w - 2.f * uu));
        }
        s = wave_reduce(s);
        if (lane == 0) e16[t] = s;
    }
    __threadfence();
    int old = 0;
    if (lane == 0) old = atomicAdd(&done1[lb], 1);
    old = __shfl(old, 0);

    // ---- Resolver 1 (last finisher) ----
    if (old == TP1 - 1) {
        __threadfence();
        double best = 1e301; int bi = 1000;
        for (int t2 = lane; t2 < TP1; t2 += 64) {
            double e = e16[t2];
            if (e < best || (e == best && t2 < bi)) { best = e; bi = t2; }
        }
        for (int off = 32; off; off >>= 1) {
            double oe = __shfl_down(best, off);
            int    oi = __shfl_down(bi, off);
            if (oe < best || (oe == best && oi < bi)) { best = oe; bi = oi; }
        }
        best = __shfl(best, 0); bi = __shfl(bi, 0);
        const double thr = best + (4.0 * EPSQ * Dd[b] + 0.05);
        int f0 = (lane < TP1) && (e16[lane] <= thr);
        int f1 = (lane + 64 < TP1) && (e16[lane + 64] <= thr);
        int f2 = (lane + 128 < TP1) && (e16[lane + 128] <= thr);
        ull m0 = __ballot(f0), m1 = __ballot(f1), m2 = __ballot(f2);
        int cnt = __popcll(m0) + __popcll(m1) + __popcll(m2);
        if (lane == 0) {
            if (cnt == 1) {
                if (!LAST && bi != 0) used[b * TP1 + bi] = 1;
                out_ids[b * LL + l] = (float)bi;
                __hip_atomic_store(&selfp[lb], bi + 1, __ATOMIC_RELEASE, __HIP_MEMORY_SCOPE_AGENT);
                __hip_atomic_store(&stat1[lb], 1, __ATOMIC_RELEASE, __HIP_MEMORY_SCOPE_AGENT);
            } else {
                maskp[0] = m0; maskp[1] = m1; maskp[2] = m2;
                scnt[lb] = cnt;
                __threadfence();
                __hip_atomic_store(&stat1[lb], 2, __ATOMIC_RELEASE, __HIP_MEMORY_SCOPE_AGENT);
            }
        }
    }

    // ---- Wait for stage-1 status ----
    int s1;
    while ((s1 = __hip_atomic_load(&stat1[lb], __ATOMIC_ACQUIRE, __HIP_MEMORY_SCOPE_AGENT)) == 0)
        __builtin_amdgcn_s_sleep(8);

    if (s1 == 2) {
        // ---- Phase B (rare): shortlist members compute exact scores ----
        const bool member = (maskp[t >> 6] >> (t & 63)) & 1ull;
        if (member) {
            double s;
            if (t == 0) {
                s = e16[0];  // already exact
            } else {
                const size_t row = ((size_t)(b * TT + t - 1)) * HW4;
                double acc = 0.0;
                #pragma unroll 4
                for (int j = lane; j < HW4; j += 64) {
                    f4 tv = temps[row + j], mv = masks[row + j], bv = bg[j];
                    f4 uu = ub[j], vv = vb[j];
                    f4 w = tv * mv + bv * (1.f - mv);
                    acc += (double)hsum(w * (vv * w - 2.f * uu));
                }
                s = wave_reduce(acc);
            }
            if (lane == 0) errx[b * TP1 + t] = s;
            __threadfence();
            int old2 = 0;
            if (lane == 0) old2 = atomicAdd(&done2[lb], 1);
            old2 = __shfl(old2, 0);
            if (old2 == scnt[lb] - 1) {
                // ---- Resolver 2 ----
                __threadfence();
                double best = 1e301; int bi = 1000;
                for (int t2 = lane; t2 < TP1; t2 += 64) {
                    if ((maskp[t2 >> 6] >> (t2 & 63)) & 1ull) {
                        double e = errx[b * TP1 + t2];
                        if (e < best || (e == best && t2 < bi)) { best = e; bi = t2; }
                    }
                }
                for (int off = 32; off; off >>= 1) {
                    double oe = __shfl_down(best, off);
                    int    oi = __shfl_down(bi, off);
                    if (oe < best || (oe == best && oi < bi)) { best = oe; bi = oi; }
                }
                if (lane == 0) {
                    if (!LAST && bi != 0) used[b * TP1 + bi] = 1;
                    out_ids[b * LL + l] = (float)bi;
                    __hip_atomic_store(&selfp[lb], bi + 1, __ATOMIC_RELEASE, __HIP_MEMORY_SCOPE_AGENT);
                }
            }
        }
        if (t >= 64 && !member) return;  // no upd duty, not needed further
    }

    if (t >= 64) return;

    // ---- Phase C: state update; block t owns f4 groups [t*64, t*64+64) ----
    int sf;
    while ((sf = __hip_atomic_load(&selfp[lb], __ATOMIC_ACQUIRE, __HIP_MEMORY_SCOPE_AGENT)) == 0)
        __builtin_amdgcn_s_sleep(8);
    const int sel = sf - 1;

    const int j = t * 64 + lane;                   // f4 group in image
    const size_t g = (size_t)b * HW4 + j;
    f4 st, sm;
    if (sel == 0) {
        st = (f4){5.f, 5.f, 5.f, 5.f};
        sm = (f4){1.f, 1.f, 1.f, 1.f};
    } else {
        size_t base = ((size_t)(b * TT + sel - 1)) * HW4 + j;
        st = temps[base];
        sm = masks[base];
    }
    f4 a = A[g], mp = M[g];
    a = a + mp * st * sm;
    mp = mp * (1.f - sm);
    const size_t ob = ((size_t)(b * LL + l)) * HW4 + j;
    out_obj[ob] = st;
    out_msk[ob] = sm;
    if (LAST) {
        out_rec[g] = a + mp * bg[j];
    } else {
        A[g] = a; M[g] = mp;
        f4 xv = x[g];
        f4* un = (f4*)u4; f4* vn = (f4*)v4;  // next-step u,v (safe: phase A of this batch done)
        un[g] = (xv - a) * mp;
        vn[g] = mp * mp;
    }
}

// Step-0 update (argmin over build's exact scores) — R6's proven k_upd<true,false>.
__global__ void k_upd0(const f4* __restrict__ temps, const f4* __restrict__ masks,
                       const f4* __restrict__ x, const double* __restrict__ err,
                       int* __restrict__ used, f4* __restrict__ A, f4* __restrict__ M,
                       f4* __restrict__ u, f4* __restrict__ v,
                       f4* __restrict__ out_obj, f4* __restrict__ out_msk,
                       float* __restrict__ out_ids) {
    const int tid = threadIdx.x;
    const int gid = blockIdx.x * 256 + tid;
    const int b = gid >> 12;
    const int p = gid & (HW4 - 1);
    __shared__ int ssel;
    if (tid < 64) {
        double best = 1e301; int bi = TP1;
        for (int t = tid; t < TP1; t += 64) {
            double e = err[b * TP1 + t];
            if (e < best) { best = e; bi = t; }
        }
        for (int off = 32; off; off >>= 1) {
            double oe = __shfl_down(best, off);
            int    oi = __shfl_down(bi, off);
            if (oe < best || (oe == best && oi < bi)) { best = oe; bi = oi; }
        }
        if (tid == 0) ssel = bi;
    }
    __syncthreads();
    const int id = ssel;
    f4 st, sm;
    if (id == 0) { st = (f4){5.f,5.f,5.f,5.f}; sm = (f4){1.f,1.f,1.f,1.f}; }
    else {
        size_t base = ((size_t)(b * TT + id - 1)) * HW4 + p;
        st = temps[base]; sm = masks[base];
    }
    f4 a = (f4){0.f,0.f,0.f,0.f}, mp = (f4){1.f,1.f,1.f,1.f};
    a = a + mp * st * sm;
    mp = mp * (1.f - sm);
    const size_t ob = ((size_t)(b * LL + 0)) * HW4 + p;
    out_obj[ob] = st;
    out_msk[ob] = sm;
    A[gid] = a; M[gid] = mp;
    f4 xv = x[gid];
    u[gid] = (xv - a) * mp;
    v[gid] = mp * mp;
    if ((blockIdx.x & 15) == 0 && tid == 0) {
        if (id != 0) used[b * TP1 + id] = 1;
        out_ids[b * LL + 0] = (float)id;
    }
}

// ---------- fallback path (small ws): R3-style exact f32 ----------
__global__ void k_err_f32(const f4* __restrict__ temps, const f4* __restrict__ masks,
                          const f4* __restrict__ bg,
                          const f4* __restrict__ u4, const f4* __restrict__ v4,
                          const int* __restrict__ used, double* __restrict__ err32) {
    const int t = blockIdx.x, b = blockIdx.y, tid = threadIdx.x;
    if (t != 0 && used[b * TP1 + t]) {
        if (tid == 0) err32[b * TP1 + t] = BIGE;
        return;
    }
    const f4* ub = u4 + (size_t)b * HW4;
    const f4* vb = v4 + (size_t)b * HW4;
    double s = 0.0;
    if (t == 0) {
        for (int j = tid; j < HW4; j += 256) {
            f4 uu = ub[j], vv = vb[j];
            s += (double)(25.f * hsum(vv) - 10.f * hsum(uu));
        }
    } else {
        const size_t row = ((size_t)(b * TT + t - 1)) * HW4;
        for (int j = tid; j < HW4; j += 256) {
            f4 tv = temps[row + j], mv = masks[row + j], bv = bg[j];
            f4 uu = ub[j], vv = vb[j];
            f4 w = tv * mv + bv * (1.f - mv);
            s += (double)hsum(w * (vv * w - 2.f * uu));
        }
    }
    double tot = blk_reduce(s);
    if (tid == 0) err32[b * TP1 + t] = tot;
}

template <bool FIRST, bool LAST>
__global__ void k_upd(const f4* __restrict__ temps, const f4* __restrict__ masks,
                      const f4* __restrict__ x, const f4* __restrict__ bg,
                      const double* __restrict__ err,
                      int* __restrict__ used, f4* __restrict__ A, f4* __restrict__ M,
                      f4* __restrict__ u, f4* __restrict__ v,
                      f4* __restrict__ out_obj, f4* __restrict__ out_msk,
                      f4* __restrict__ out_rec, float* __restrict__ out_ids, int l) {
    const int tid = threadIdx.x;
    const int gid = blockIdx.x * 256 + tid;
    const int b = gid >> 12;
    const int p = gid & (HW4 - 1);
    __shared__ int ssel;
    if (tid < 64) {
        double best = 1e301; int bi = TP1;
        for (int t = tid; t < TP1; t += 64) {
            double e = err[b * TP1 + t];
            if (e < best) { best = e; bi = t; }
        }
        for (int off = 32; off; off >>= 1) {
            double oe = __shfl_down(best, off);
            int    oi = __shfl_down(bi, off);
            if (oe < best || (oe == best && oi < bi)) { best = oe; bi = oi; }
        }
        if (tid == 0) ssel = bi;
    }
    __syncthreads();
    const int id = ssel;
    f4 st, sm;
    if (id == 0) { st = (f4){5.f,5.f,5.f,5.f}; sm = (f4){1.f,1.f,1.f,1.f}; }
    else {
        size_t base = ((size_t)(b * TT + id - 1)) * HW4 + p;
        st = temps[base]; sm = masks[base];
    }
    f4 a, mp;
    if (FIRST) { a = (f4){0.f,0.f,0.f,0.f}; mp = (f4){1.f,1.f,1.f,1.f}; }
    else       { a = A[gid]; mp = M[gid]; }
    a = a + mp * st * sm;
    mp = mp * (1.f - sm);
    const size_t ob = ((size_t)(b * LL + l)) * HW4 + p;
    out_obj[ob] = st;
    out_msk[ob] = sm;
    if (LAST) {
        out_rec[gid] = a + mp * bg[p];
    } else {
        A[gid] = a; M[gid] = mp;
        f4 xv = x[gid];
        u[gid] = (xv - a) * mp;
        v[gid] = mp * mp;
    }
    if ((blockIdx.x & 15) == 0 && tid == 0) {
        if (id != 0) used[b * TP1 + id] = 1;
        out_ids[b * LL + l] = (float)id;
    }
}

__global__ void k_uv0(const f4* __restrict__ x, f4* __restrict__ u, f4* __restrict__ v,
                      int* __restrict__ used) {
    int gid = blockIdx.x * blockDim.x + threadIdx.x;
    if (gid < BB * TP1) used[gid] = 0;
    if (gid >= BB * HW4) return;
    u[gid] = x[gid];
    v[gid] = (f4){1.f, 1.f, 1.f, 1.f};
}

extern "C" void kernel_launch(void* const* d_in, const int* in_sizes, int n_in,
                              void* d_out, int out_size, void* d_ws, size_t ws_size,
                              hipStream_t stream) {
    const f4* x     = (const f4*)d_in[0];
    const f4* temps = (const f4*)d_in[1];
    const f4* masks = (const f4*)d_in[2];
    const f4* bg    = (const f4*)d_in[3];

    float* out      = (float*)d_out;
    f4*    out_rec  = (f4*)out;                           // B*HW
    f4*    out_obj  = (f4*)(out + 262144);                // B*L*HW
    f4*    out_msk  = (f4*)(out + 262144 + 1572864);      // B*L*HW
    float* out_ids  = out + 262144 + 2 * 1572864;         // B*L

    char* ws = (char*)d_ws;
    f4*     A     = (f4*)(ws + OFF_A);
    f4*     M     = (f4*)(ws + OFF_M);
    f4*     u     = (f4*)(ws + OFF_U);
    f4*     v     = (f4*)(ws + OFF_V);
    double* err32 = (double*)(ws + OFF_ERR32);
    double* err16 = (double*)(ws + OFF_ERR16);
    double* errx  = (double*)(ws + OFF_ERRX);
    double* Dd    = (double*)(ws + OFF_D);
    int*    used  = (int*)(ws + OFF_USED);
    int*    prot  = (int*)(ws + OFF_PROT);
    u16x4*  wq    = (u16x4*)(ws + OFF_WQ);

    const bool full = (ws_size >= WS_FULL);

    if (full) {
        k_build<<<dim3(TP1, BB), 256, 0, stream>>>(temps, masks, bg, x, wq, err32, used, prot);
        k_upd0<<<256, 256, 0, stream>>>(temps, masks, x, err32, used, A, M, u, v,
                                        out_obj, out_msk, out_ids);
        for (int l = 1; l < LL; ++l) {
            if (l < LL - 1)
                k_fstep<false><<<BB * TP1, 64, 0, stream>>>(
                    temps, masks, bg, x, (const u16x8*)wq, u, v, A, M,
                    used, err16, errx, Dd, prot, out_obj, out_msk, out_rec, out_ids, l);
            else
                k_fstep<true><<<BB * TP1, 64, 0, stream>>>(
                    temps, masks, bg, x, (const u16x8*)wq, u, v, A, M,
                    used, err16, errx, Dd, prot, out_obj, out_msk, out_rec, out_ids, l);
        }
    } else {
        k_uv0<<<(BB * HW4 + 255) / 256, 256, 0, stream>>>(x, u, v, used);
        for (int l = 0; l < LL; ++l) {
            k_err_f32<<<dim3(TP1, BB), 256, 0, stream>>>(temps, masks, bg, u, v, used, err32);
            if (l == 0)
                k_upd<true, false><<<256, 256, 0, stream>>>(temps, masks, x, bg, err32, used, A, M, u, v, out_obj, out_msk, out_rec, out_ids, l);
            else if (l == LL - 1)
                k_upd<false, true><<<256, 256, 0, stream>>>(temps, masks, x, bg, err32, used, A, M, u, v, out_obj, out_msk, out_rec, out_ids, l);
            else
                k_upd<false, false><<<256, 256, 0, stream>>>(temps, masks, x, bg, err32, used, A, M, u, v, out_obj, out_msk, out_rec, out_ids, l);
        }
    }
}

// Round 8
// 240.776 us; speedup vs baseline: 17.1417x; 17.1417x over previous
//
#include <hip/hip_runtime.h>
#include <math.h>

#define BB 16
#define TT 144
#define TP1 145
#define HW4 4096   // f4 groups per image
#define HW8 2048   // f8/u16x8 groups per image
#define LL 6
#define BIGE 1e30
#define EPSQ 7.62951e-6  // 0.5/65535 quantization bound on w in [0,1]
#define RB 37            // 36 blocks of 4 t-rows + 1 special (t=0/D) block per batch
#define NBLK (BB * RB)   // 592
#define BCHUNK 74        // 592/8 XCDs (bijective)
#define RCHUNK 290       // 2320/8

typedef float          f4    __attribute__((ext_vector_type(4)));
typedef float          f8    __attribute__((ext_vector_type(8)));
typedef unsigned short u16x4 __attribute__((ext_vector_type(4)));
typedef unsigned short u16x8 __attribute__((ext_vector_type(8)));

// ---- workspace layout (bytes) ----
// State streams: Ms = M*(1/65535), r = x - A  (M, A reconstructed: M=65535*Ms, A=x-r)
static const size_t OFF_MS   = 0;                   // B*HW f32 (1 MB)
static const size_t OFF_R    = 1u << 20;            // B*HW f32
static const size_t OFF_E32  = 2u << 20;            // B*145 f64 (exact/refined scores)
static const size_t OFF_E16  = (2u << 20) + 32768;  // B*145 f64 (screen scores)
static const size_t OFF_D    = (2u << 20) + 65536;  // B f64 (margin accumulator)
static const size_t OFF_USED = (2u << 20) + 81920;  // B*145 i32
static const size_t OFF_WQ   = 3u << 20;            // B*T*HW u16 = 75,497,472
static const size_t WS_FULL  = OFF_WQ + 75497472ull;

__device__ __forceinline__ float hsum(f4 v) { return ((v.x + v.y) + v.z) + v.w; }
__device__ __forceinline__ float hsum8(f8 v) {
    return (((v.s0 + v.s1) + (v.s2 + v.s3)) + ((v.s4 + v.s5) + (v.s6 + v.s7)));
}
__device__ __forceinline__ f8 fabs8(f8 v) {
    f8 o;
    o.s0 = __builtin_fabsf(v.s0); o.s1 = __builtin_fabsf(v.s1);
    o.s2 = __builtin_fabsf(v.s2); o.s3 = __builtin_fabsf(v.s3);
    o.s4 = __builtin_fabsf(v.s4); o.s5 = __builtin_fabsf(v.s5);
    o.s6 = __builtin_fabsf(v.s6); o.s7 = __builtin_fabsf(v.s7);
    return o;
}

__device__ __forceinline__ double blk_reduce(double s) {
    for (int off = 32; off; off >>= 1) s += __shfl_down(s, off);
    __shared__ double smr[4];
    if ((threadIdx.x & 63) == 0) smr[threadIdx.x >> 6] = s;
    __syncthreads();
    return smr[0] + smr[1] + smr[2] + smr[3];
}

__device__ __forceinline__ void blk_reduce2(double& a, double& b) {
    for (int off = 32; off; off >>= 1) { a += __shfl_down(a, off); b += __shfl_down(b, off); }
    __shared__ double sa[4], sb[4];
    if ((threadIdx.x & 63) == 0) { sa[threadIdx.x >> 6] = a; sb[threadIdx.x >> 6] = b; }
    __syncthreads();
    a = sa[0] + sa[1] + sa[2] + sa[3];
    b = sb[0] + sb[1] + sb[2] + sb[3];
}

__device__ __forceinline__ void blk_reduce4(double s[4]) {
    for (int off = 32; off; off >>= 1) {
        s[0] += __shfl_down(s[0], off); s[1] += __shfl_down(s[1], off);
        s[2] += __shfl_down(s[2], off); s[3] += __shfl_down(s[3], off);
    }
    __shared__ double sm4[4][4];
    const int wv = threadIdx.x >> 6;
    if ((threadIdx.x & 63) == 0) {
        sm4[wv][0] = s[0]; sm4[wv][1] = s[1]; sm4[wv][2] = s[2]; sm4[wv][3] = s[3];
    }
    __syncthreads();
    for (int k = 0; k < 4; ++k) s[k] = sm4[0][k] + sm4[1][k] + sm4[2][k] + sm4[3][k];
}

// Build wq = u16(round(65535*w)), w = t*m + bg*(1-m), 4 t-rows per block
// (cuts x/bg L2 broadcast 4x); exact step-0 scores err32 = sum((w-x)^2); zero used[].
__global__ void k_build(const f4* __restrict__ temps, const f4* __restrict__ masks,
                        const f4* __restrict__ bg, const f4* __restrict__ x,
                        u16x4* __restrict__ wq, double* __restrict__ err32,
                        int* __restrict__ used) {
    const int lin = blockIdx.x;
    const int wg = (lin & 7) * BCHUNK + (lin >> 3);   // XCD-chunked bijective swizzle
    const int b = wg / RB, rg = wg - b * RB;
    const int tid = threadIdx.x;
    const f4* xb = x + (size_t)b * HW4;
    if (rg == RB - 1) {   // t = 0: w = 5 exactly
        if (tid < TP1) used[b * TP1 + tid] = 0;
        double s = 0.0;
        for (int j = tid; j < HW4; j += 256) {
            f4 d = 5.f - xb[j];
            s += (double)hsum(d * d);
        }
        double tot = blk_reduce(s);
        if (tid == 0) err32[b * TP1 + 0] = tot;
        return;
    }
    const int tbase = 1 + rg * 4;
    const size_t r0 = ((size_t)(b * TT + tbase - 1)) * HW4;
    const size_t r1 = r0 + HW4, r2 = r1 + HW4, r3 = r2 + HW4;
    double s[4] = {0.0, 0.0, 0.0, 0.0};
    #pragma unroll 2
    for (int j = tid; j < HW4; j += 256) {
        f4 bv = bg[j], xv = xb[j];
        f4 tv0 = __builtin_nontemporal_load(&temps[r0 + j]);
        f4 mv0 = __builtin_nontemporal_load(&masks[r0 + j]);
        f4 w0 = tv0 * mv0 + bv * (1.f - mv0);
        wq[r0 + j] = __builtin_convertvector(w0 * 65535.f + 0.5f, u16x4);
        f4 d0 = w0 - xv; s[0] += (double)hsum(d0 * d0);
        f4 tv1 = __builtin_nontemporal_load(&temps[r1 + j]);
        f4 mv1 = __builtin_nontemporal_load(&masks[r1 + j]);
        f4 w1 = tv1 * mv1 + bv * (1.f - mv1);
        wq[r1 + j] = __builtin_convertvector(w1 * 65535.f + 0.5f, u16x4);
        f4 d1 = w1 - xv; s[1] += (double)hsum(d1 * d1);
        f4 tv2 = __builtin_nontemporal_load(&temps[r2 + j]);
        f4 mv2 = __builtin_nontemporal_load(&masks[r2 + j]);
        f4 w2 = tv2 * mv2 + bv * (1.f - mv2);
        wq[r2 + j] = __builtin_convertvector(w2 * 65535.f + 0.5f, u16x4);
        f4 d2 = w2 - xv; s[2] += (double)hsum(d2 * d2);
        f4 tv3 = __builtin_nontemporal_load(&temps[r3 + j]);
        f4 mv3 = __builtin_nontemporal_load(&masks[r3 + j]);
        f4 w3 = tv3 * mv3 + bv * (1.f - mv3);
        wq[r3 + j] = __builtin_convertvector(w3 * 65535.f + 0.5f, u16x4);
        f4 d3 = w3 - xv; s[3] += (double)hsum(d3 * d3);
    }
    blk_reduce4(s);
    if (tid == 0)
        for (int k = 0; k < 4; ++k) err32[b * TP1 + tbase + k] = s[k];
}

// Screen pass, 4 t-rows per block: score = sum(d^2), d = fma(q, Ms, -r)
// (the 1/65535 dequant cancels against Ms = M/65535). t0 block: exact t=0 score
// + D = sum(M*(M+|r|)) for the sound margin.
__global__ void k_errs(const u16x8* __restrict__ wq,
                       const f8* __restrict__ Ms, const f8* __restrict__ R,
                       const int* __restrict__ used,
                       double* __restrict__ err16, double* __restrict__ Dd) {
    const int lin = blockIdx.x;
    const int wg = (lin & 7) * BCHUNK + (lin >> 3);
    const int b = wg / RB, rg = wg - b * RB;
    const int tid = threadIdx.x;
    const f8* msb = Ms + (size_t)b * HW8;
    const f8* rb  = R  + (size_t)b * HW8;
    if (rg == RB - 1) {
        double s = 0.0, d = 0.0;
        for (int j = tid; j < HW8; j += 256) {
            f8 ms = msb[j], rr = rb[j];
            f8 M = ms * 65535.f;
            f8 dd = M * 5.f - rr;
            s += (double)hsum8(dd * dd);
            d += (double)hsum8(M * (M + fabs8(rr)));
        }
        blk_reduce2(s, d);
        if (tid == 0) { err16[b * TP1 + 0] = s; Dd[b] = d; }
        return;
    }
    const int tbase = 1 + rg * 4;
    const size_t r0 = ((size_t)(b * TT + tbase - 1)) * HW8;
    const size_t r1 = r0 + HW8, r2 = r1 + HW8, r3 = r2 + HW8;
    double s[4] = {0.0, 0.0, 0.0, 0.0};
    #pragma unroll 2
    for (int j = tid; j < HW8; j += 256) {
        f8 ms = msb[j], rr = rb[j];
        f8 q0 = __builtin_convertvector(wq[r0 + j], f8);
        f8 d0 = q0 * ms - rr; s[0] += (double)hsum8(d0 * d0);
        f8 q1 = __builtin_convertvector(wq[r1 + j], f8);
        f8 d1 = q1 * ms - rr; s[1] += (double)hsum8(d1 * d1);
        f8 q2 = __builtin_convertvector(wq[r2 + j], f8);
        f8 d2 = q2 * ms - rr; s[2] += (double)hsum8(d2 * d2);
        f8 q3 = __builtin_convertvector(wq[r3 + j], f8);
        f8 d3 = q3 * ms - rr; s[3] += (double)hsum8(d3 * d3);
    }
    blk_reduce4(s);
    if (tid == 0)
        for (int k = 0; k < 4; ++k) {
            int t = tbase + k;
            err16[b * TP1 + t] = used[b * TP1 + t] ? BIGE : s[k];
        }
}

// Sound refine (proven R6 logic, d-form): shortlist = {t: s <= min + margin};
// singleton -> screen argmin IS the true argmin, no re-eval; else exact f32 eval.
__global__ void k_refine(const f4* __restrict__ temps, const f4* __restrict__ masks,
                         const f4* __restrict__ bg,
                         const f4* __restrict__ Ms4, const f4* __restrict__ R4,
                         const double* __restrict__ err16, const double* __restrict__ Dd,
                         double* __restrict__ err32) {
    const int lin = blockIdx.x;
    const int wg = (lin & 7) * RCHUNK + (lin >> 3);
    const int b = wg / TP1, t = wg - b * TP1;
    const int tid = threadIdx.x;
    double e = (tid < TP1) ? err16[b * TP1 + tid] : 1e300;
    double m = e;
    for (int off = 32; off; off >>= 1) {
        double o = __shfl_down(m, off);
        m = (o < m) ? o : m;
    }
    __shared__ double sm[4]; __shared__ double smin_s; __shared__ int scnt[4];
    if ((tid & 63) == 0) sm[tid >> 6] = m;
    __syncthreads();
    if (tid == 0) {
        double a = (sm[0] < sm[1]) ? sm[0] : sm[1];
        double c = (sm[2] < sm[3]) ? sm[2] : sm[3];
        smin_s = (a < c) ? a : c;
    }
    __syncthreads();
    const double thr = smin_s + (6.0 * EPSQ * Dd[b] + 0.15);
    int flag = (tid < TP1) && (e <= thr);
    unsigned long long bal = __ballot(flag);
    if ((tid & 63) == 0) scnt[tid >> 6] = __popcll(bal);
    __syncthreads();
    const int cnt = scnt[0] + scnt[1] + scnt[2] + scnt[3];
    const double mys = err16[b * TP1 + t];
    if (mys > thr) { if (tid == 0) err32[b * TP1 + t] = BIGE; return; }
    if (cnt == 1 || t == 0) { if (tid == 0) err32[b * TP1 + t] = mys; return; }
    const size_t row = ((size_t)(b * TT + t - 1)) * HW4;
    const f4* msb = Ms4 + (size_t)b * HW4;
    const f4* rb  = R4  + (size_t)b * HW4;
    double s = 0.0;
    for (int j = tid; j < HW4; j += 256) {
        f4 tv = temps[row + j], mv = masks[row + j], bv = bg[j];
        f4 w = tv * mv + bv * (1.f - mv);
        f4 M = msb[j] * 65535.f;
        f4 d = w * M - rb[j];
        s += (double)hsum(d * d);
    }
    double tot = blk_reduce(s);
    if (tid == 0) err32[b * TP1 + t] = tot;
}

// Fused argmin + state update (Ms,r streams) + object emit + bookkeeping.
// LAST step emits recons = A + M*bg (affine dead-leaves identity).
template <bool FIRST, bool LAST>
__global__ void k_upd(const f4* __restrict__ temps, const f4* __restrict__ masks,
                      const f4* __restrict__ x, const f4* __restrict__ bg,
                      const double* __restrict__ err,
                      int* __restrict__ used, f4* __restrict__ Ms4, f4* __restrict__ R4,
                      f4* __restrict__ out_obj, f4* __restrict__ out_msk,
                      f4* __restrict__ out_rec, float* __restrict__ out_ids, int l) {
    const int lin = blockIdx.x;
    const int wg = (lin & 7) * 32 + (lin >> 3);    // 256 = 8*32 bijective
    const int tid = threadIdx.x;
    const int gid = wg * 256 + tid;
    const int b = gid >> 12;
    const int p = gid & (HW4 - 1);
    __shared__ int ssel;
    if (tid < 64) {
        double best = 1e301; int bi = TP1;
        for (int t = tid; t < TP1; t += 64) {
            double e = err[b * TP1 + t];
            if (e < best) { best = e; bi = t; }   // ascending t per thread: < keeps first
        }
        for (int off = 32; off; off >>= 1) {
            double oe = __shfl_down(best, off);
            int    oi = __shfl_down(bi, off);
            if (oe < best || (oe == best && oi < bi)) { best = oe; bi = oi; }
        }
        if (tid == 0) ssel = bi;
    }
    __syncthreads();
    const int id = ssel;
    f4 st, sm_;
    if (id == 0) { st = (f4){5.f,5.f,5.f,5.f}; sm_ = (f4){1.f,1.f,1.f,1.f}; }
    else {
        size_t base = ((size_t)(b * TT + id - 1)) * HW4 + p;
        st = temps[base]; sm_ = masks[base];
    }
    f4 xv = x[gid];
    f4 a, mp;
    if (FIRST) { a = (f4){0.f,0.f,0.f,0.f}; mp = (f4){1.f,1.f,1.f,1.f}; }
    else       { mp = Ms4[gid] * 65535.f; a = xv - R4[gid]; }
    a = a + mp * st * sm_;
    mp = mp * (1.f - sm_);
    const size_t ob = ((size_t)(b * LL + l)) * HW4 + p;
    out_obj[ob] = st;
    out_msk[ob] = sm_;
    if (LAST) {
        out_rec[gid] = a + mp * bg[p];
    } else {
        Ms4[gid] = mp * (1.f / 65535.f);
        R4[gid]  = xv - a;
    }
    if ((wg & 15) == 0 && tid == 0) {   // one block per batch
        if (id != 0) used[b * TP1 + id] = 1;
        out_ids[b * LL + l] = (float)id;
    }
}

// ---------- fallback path (small ws): exact d-form per (b,t) ----------
__global__ void k_init0(const f4* __restrict__ x, f4* __restrict__ Ms4, f4* __restrict__ R4,
                        int* __restrict__ used) {
    int gid = blockIdx.x * blockDim.x + threadIdx.x;
    if (gid < BB * TP1) used[gid] = 0;
    if (gid >= BB * HW4) return;
    float msv = (float)(1.0 / 65535.0);
    Ms4[gid] = (f4){msv, msv, msv, msv};
    R4[gid] = x[gid];
}

__global__ void k_errfb(const f4* __restrict__ temps, const f4* __restrict__ masks,
                        const f4* __restrict__ bg,
                        const f4* __restrict__ Ms4, const f4* __restrict__ R4,
                        const int* __restrict__ used, double* __restrict__ err32) {
    const int lin = blockIdx.x;
    const int wg = (lin & 7) * RCHUNK + (lin >> 3);
    const int b = wg / TP1, t = wg - b * TP1;
    const int tid = threadIdx.x;
    if (t != 0 && used[b * TP1 + t]) {
        if (tid == 0) err32[b * TP1 + t] = BIGE;
        return;
    }
    const f4* msb = Ms4 + (size_t)b * HW4;
    const f4* rb  = R4  + (size_t)b * HW4;
    double s = 0.0;
    if (t == 0) {
        for (int j = tid; j < HW4; j += 256) {
            f4 M = msb[j] * 65535.f;
            f4 d = M * 5.f - rb[j];
            s += (double)hsum(d * d);
        }
    } else {
        const size_t row = ((size_t)(b * TT + t - 1)) * HW4;
        for (int j = tid; j < HW4; j += 256) {
            f4 tv = temps[row + j], mv = masks[row + j], bv = bg[j];
            f4 w = tv * mv + bv * (1.f - mv);
            f4 M = msb[j] * 65535.f;
            f4 d = w * M - rb[j];
            s += (double)hsum(d * d);
        }
    }
    double tot = blk_reduce(s);
    if (tid == 0) err32[b * TP1 + t] = tot;
}

extern "C" void kernel_launch(void* const* d_in, const int* in_sizes, int n_in,
                              void* d_out, int out_size, void* d_ws, size_t ws_size,
                              hipStream_t stream) {
    const f4* x     = (const f4*)d_in[0];
    const f4* temps = (const f4*)d_in[1];
    const f4* masks = (const f4*)d_in[2];
    const f4* bg    = (const f4*)d_in[3];

    float* out      = (float*)d_out;
    f4*    out_rec  = (f4*)out;                           // B*HW
    f4*    out_obj  = (f4*)(out + 262144);                // B*L*HW
    f4*    out_msk  = (f4*)(out + 262144 + 1572864);      // B*L*HW
    float* out_ids  = out + 262144 + 2 * 1572864;         // B*L

    char* ws = (char*)d_ws;
    f4*     Ms4   = (f4*)(ws + OFF_MS);
    f4*     R4    = (f4*)(ws + OFF_R);
    double* err32 = (double*)(ws + OFF_E32);
    double* err16 = (double*)(ws + OFF_E16);
    double* Dd    = (double*)(ws + OFF_D);
    int*    used  = (int*)(ws + OFF_USED);
    u16x4*  wq    = (u16x4*)(ws + OFF_WQ);

    const bool full = (ws_size >= WS_FULL);

    if (full) {
        k_build<<<NBLK, 256, 0, stream>>>(temps, masks, bg, x, wq, err32, used);
        k_upd<true, false><<<256, 256, 0, stream>>>(temps, masks, x, bg, err32, used,
                                                    Ms4, R4, out_obj, out_msk, out_rec, out_ids, 0);
        for (int l = 1; l < LL; ++l) {
            k_errs<<<NBLK, 256, 0, stream>>>((const u16x8*)wq, (const f8*)Ms4, (const f8*)R4,
                                             used, err16, Dd);
            k_refine<<<BB * TP1, 256, 0, stream>>>(temps, masks, bg, Ms4, R4, err16, Dd, err32);
            if (l < LL - 1)
                k_upd<false, false><<<256, 256, 0, stream>>>(temps, masks, x, bg, err32, used,
                                                             Ms4, R4, out_obj, out_msk, out_rec, out_ids, l);
            else
                k_upd<false, true><<<256, 256, 0, stream>>>(temps, masks, x, bg, err32, used,
                                                            Ms4, R4, out_obj, out_msk, out_rec, out_ids, l);
        }
    } else {
        k_init0<<<(BB * HW4 + 255) / 256, 256, 0, stream>>>(x, Ms4, R4, used);
        for (int l = 0; l < LL; ++l) {
            k_errfb<<<BB * TP1, 256, 0, stream>>>(temps, masks, bg, Ms4, R4, used, err32);
            if (l == 0)
                k_upd<true, false><<<256, 256, 0, stream>>>(temps, masks, x, bg, err32, used,
                                                            Ms4, R4, out_obj, out_msk, out_rec, out_ids, l);
            else if (l == LL - 1)
                k_upd<false, true><<<256, 256, 0, stream>>>(temps, masks, x, bg, err32, used,
                                                            Ms4, R4, out_obj, out_msk, out_rec, out_ids, l);
            else
                k_upd<false, false><<<256, 256, 0, stream>>>(temps, masks, x, bg, err32, used,
                                                             Ms4, R4, out_obj, out_msk, out_rec, out_ids, l);
        }
    }
}